// Round 8
// baseline (670.494 us; speedup 1.0000x reference)
//
#include <hip/hip_runtime.h>

// LightGCN propagation on MI355X — R16: R13 base (R15 masked tail reverted:
// +13MB FETCH, +2us — tail latency wasn't binding) + non-temporal hints on
// every zero-reuse stream in the spmm kernels.
//
// Theory: spmm FETCH=384MB = half of the 768MB gather demand missing L2.
// The 19.2MB cur table would fit better in the 8x4MB L2s if the 48MB pairs
// stream and 19-38MB output stream (zero reuse) didn't continuously evict it.
// NT-mark pairs loads, nxt stores, e1b/acc loads+stores; cur gathers stay
// cached. Bit-identical math.
//
// Inputs: [2] adj_src (6M int), [3] adj_dst (6M int), [4] adj_vals (6M f32),
//         [5] user_emb (100000x64 f32), [6] item_emb (50000x64 f32).
// Output: [150000x64] f32 = (e0+e1+e2+e3)/4.

#define NUM_USERS 100000
#define NUM_ITEMS 50000
#define N_NODES   150000
#define EMB       64
#define N_EDGES   6000000

#define ROWS_PER_B 256
#define NBUCKETS   586                        // ceil(150000/256)
#define NROWS_PAD  (NBUCKETS * ROWS_PER_B)    // 150016
#define PART_BLOCKS 512
#define CHUNK ((N_EDGES + PART_BLOCKS - 1) / PART_BLOCKS)   // 11719
#define CAP_B 10952                           // 10240 + 7 sigma, padded bucket cap

constexpr int NODE_F4 = N_NODES * EMB / 4;   // 2,400,000
constexpr int USER_F4 = NUM_USERS * EMB / 4; // 1,600,000

typedef float f4v __attribute__((ext_vector_type(4)));   // 16B clang vector

__device__ __forceinline__ float bf2f(unsigned short u) {
    union { unsigned int i; float f; } x; x.i = ((unsigned int)u) << 16; return x.f;
}
__device__ __forceinline__ unsigned short f2bf(float f) {
    union { float f; unsigned int i; } x; x.f = f;
    unsigned int b = x.i;
    return (unsigned short)((b + 0x7FFFu + ((b >> 16) & 1u)) >> 16);  // RNE
}

// ================= tier-1 (padded-bucket) kernels =================

__global__ void k_ginit(int* __restrict__ gcur) {
    int i = blockIdx.x * blockDim.x + threadIdx.x;
    if (i < NBUCKETS) gcur[i] = i * CAP_B;
}

// self-count + claim + scatter (R10-proven structure; bases claimed from
// gcur pre-set to k*CAP — no pre-counting kernels needed)
__global__ __launch_bounds__(256) void k_part(const int* __restrict__ src,
                                              const int* __restrict__ dst,
                                              const float* __restrict__ val,
                                              int* __restrict__ gcur,
                                              int2* __restrict__ pairs) {
    __shared__ int cnt[NBUCKETS];
    __shared__ int base[NBUCKETS];
    int t = threadIdx.x;
    for (int i = t; i < NBUCKETS; i += 256) cnt[i] = 0;
    __syncthreads();
    int e0 = blockIdx.x * CHUNK;
    int e1 = min(e0 + CHUNK, N_EDGES);
    {
        int e = e0 + t;
        for (; e + 7 * 256 < e1; e += 8 * 256) {
            int b_[8];
#pragma unroll
            for (int j = 0; j < 8; ++j)
                b_[j] = __builtin_nontemporal_load(dst + e + j * 256) >> 8;
#pragma unroll
            for (int j = 0; j < 8; ++j) atomicAdd(&cnt[b_[j]], 1);
        }
        for (; e < e1; e += 256)
            atomicAdd(&cnt[__builtin_nontemporal_load(dst + e) >> 8], 1);
    }
    __syncthreads();
    for (int i = t; i < NBUCKETS; i += 256) {
        int c = cnt[i];
        base[i] = c ? atomicAdd(&gcur[i], c) : 0;
        cnt[i] = 0;
    }
    __syncthreads();
    {
        int e = e0 + t;
        for (; e + 7 * 256 < e1; e += 8 * 256) {
            int d_[8], s_[8];
            float v_[8];
#pragma unroll
            for (int j = 0; j < 8; ++j)
                d_[j] = __builtin_nontemporal_load(dst + e + j * 256);
#pragma unroll
            for (int j = 0; j < 8; ++j)
                s_[j] = __builtin_nontemporal_load(src + e + j * 256);
#pragma unroll
            for (int j = 0; j < 8; ++j)
                v_[j] = __builtin_nontemporal_load(val + e + j * 256);
#pragma unroll
            for (int j = 0; j < 8; ++j) {
                int b_ = d_[j] >> 8;
                int o = atomicAdd(&cnt[b_], 1);
                pairs[base[b_] + o] = make_int2(s_[j] | ((d_[j] & 255) << 18),
                                                __float_as_int(v_[j]));
            }
        }
        for (; e < e1; e += 256) {
            int d0 = __builtin_nontemporal_load(dst + e);
            int s0 = __builtin_nontemporal_load(src + e);
            float v0 = __builtin_nontemporal_load(val + e);
            int b_ = d0 >> 8;
            int o0 = atomicAdd(&cnt[b_], 1);
            pairs[base[b_] + o0] = make_int2(s0 | ((d0 & 255) << 18),
                                             __float_as_int(v0));
        }
    }
}

// fills = gcur[k] - k*CAP -> exclusive scan -> exact dense bucket offsets
__global__ void k_fill(const int* __restrict__ gcur, int* __restrict__ boff) {
    __shared__ int s[1024];
    int t = threadIdx.x;
    int x = (t < NBUCKETS) ? (gcur[t] - t * CAP_B) : 0;
    s[t] = x;
    __syncthreads();
    for (int off = 1; off < 1024; off <<= 1) {
        int v = (t >= off) ? s[t - off] : 0;
        __syncthreads();
        s[t] += v;
        __syncthreads();
    }
    if (t < NBUCKETS) boff[t] = s[t] - x;
    if (t == 0) boff[NBUCKETS] = N_EDGES;
}

// per-bucket row sort from padded source range; 1024 threads.
__global__ __launch_bounds__(1024) void k_sortA(const int* __restrict__ gcur,
                                                const int* __restrict__ boff,
                                                const int2* __restrict__ pairs1,
                                                int2* __restrict__ pairs2,
                                                int* __restrict__ row_ptr) {
    __shared__ int cnt[ROWS_PER_B];    // counts, then cursors
    __shared__ int s[ROWS_PER_B];
    int b = blockIdx.x;
    int t = threadIdx.x;
    if (t < ROWS_PER_B) cnt[t] = 0;
    __syncthreads();
    int beg = b * CAP_B;
    int end = gcur[b];
    {
        int e = beg + t;
        for (; e + 7 * 1024 < end; e += 8 * 1024) {
            int r_[8];
#pragma unroll
            for (int j = 0; j < 8; ++j)
                r_[j] = ((unsigned)pairs1[e + j * 1024].x) >> 18;  // cached: reused by pass 2
#pragma unroll
            for (int j = 0; j < 8; ++j) atomicAdd(&cnt[r_[j]], 1);
        }
        for (; e < end; e += 1024)
            atomicAdd(&cnt[((unsigned)pairs1[e].x) >> 18], 1);
    }
    __syncthreads();
    int x = (t < ROWS_PER_B) ? cnt[t] : 0;
    if (t < ROWS_PER_B) s[t] = x;
    __syncthreads();
    for (int off = 1; off < ROWS_PER_B; off <<= 1) {
        int v = (t >= off && t < ROWS_PER_B) ? s[t - off] : 0;
        __syncthreads();
        if (t < ROWS_PER_B) s[t] += v;
        __syncthreads();
    }
    if (t < ROWS_PER_B) {
        int ex = boff[b] + s[t] - x;
        row_ptr[b * ROWS_PER_B + t] = ex;
        cnt[t] = ex;
    }
    if (b == NBUCKETS - 1 && t == 0) row_ptr[NROWS_PAD] = N_EDGES;
    __syncthreads();
    const long* p1l = (const long*)pairs1;
    {
        int e = beg + t;
        for (; e + 7 * 1024 < end; e += 8 * 1024) {
            long q[8];
#pragma unroll
            for (int j = 0; j < 8; ++j)
                q[j] = __builtin_nontemporal_load(p1l + e + j * 1024);  // last read: NT
#pragma unroll
            for (int j = 0; j < 8; ++j) {
                int x0 = (int)q[j], y0 = (int)(q[j] >> 32);
                int pos = atomicAdd(&cnt[((unsigned)x0) >> 18], 1);
                pairs2[pos] = make_int2(x0 & 0x3FFFF, y0);
            }
        }
        for (; e < end; e += 1024) {
            long q0 = __builtin_nontemporal_load(p1l + e);
            int x0 = (int)q0, y0 = (int)(q0 >> 32);
            int pos = atomicAdd(&cnt[((unsigned)x0) >> 18], 1);
            pairs2[pos] = make_int2(x0 & 0x3FFFF, y0);
        }
    }
}

// ================= tier-2 (R12 exact) kernels =================

__global__ void k_zero(int* __restrict__ p, int n) {
    int i = blockIdx.x * blockDim.x + threadIdx.x;
    if (i < n) p[i] = 0;
}

__global__ __launch_bounds__(256) void k_bhist(const int* __restrict__ dst,
                                               int* __restrict__ gcnt,
                                               int* __restrict__ cnt_pb) {
    __shared__ int cnt[NBUCKETS];
    int t = threadIdx.x;
    for (int i = t; i < NBUCKETS; i += 256) cnt[i] = 0;
    __syncthreads();
    int e0 = blockIdx.x * CHUNK;
    int e1 = min(e0 + CHUNK, N_EDGES);
    int e = e0 + t;
    for (; e + 7 * 256 < e1; e += 8 * 256) {
        int b_[8];
#pragma unroll
        for (int j = 0; j < 8; ++j)
            b_[j] = __builtin_nontemporal_load(dst + e + j * 256) >> 8;
#pragma unroll
        for (int j = 0; j < 8; ++j) atomicAdd(&cnt[b_[j]], 1);
    }
    for (; e < e1; e += 256)
        atomicAdd(&cnt[__builtin_nontemporal_load(dst + e) >> 8], 1);
    __syncthreads();
    for (int i = t; i < NBUCKETS; i += 256) {
        int c = cnt[i];
        cnt_pb[blockIdx.x * NBUCKETS + i] = c;
        if (c) atomicAdd(&gcnt[i], c);
    }
}

__global__ void k_bscan(const int* __restrict__ gcnt, int* __restrict__ boff) {
    __shared__ int s[1024];
    int t = threadIdx.x;
    int x = (t < NBUCKETS) ? gcnt[t] : 0;
    s[t] = x;
    __syncthreads();
    for (int off = 1; off < 1024; off <<= 1) {
        int v = (t >= off) ? s[t - off] : 0;
        __syncthreads();
        s[t] += v;
        __syncthreads();
    }
    if (t < NBUCKETS) boff[t] = s[t] - x;
    if (t == 0) boff[NBUCKETS] = N_EDGES;
}

__global__ __launch_bounds__(512) void k_pscan(const int* __restrict__ boff,
                                               int* __restrict__ cnt_pb) {
    __shared__ int s[PART_BLOCKS];
    int k = blockIdx.x;
    int t = threadIdx.x;
    int x = cnt_pb[t * NBUCKETS + k];
    s[t] = x;
    __syncthreads();
    for (int off = 1; off < PART_BLOCKS; off <<= 1) {
        int v = (t >= off) ? s[t - off] : 0;
        __syncthreads();
        s[t] += v;
        __syncthreads();
    }
    cnt_pb[t * NBUCKETS + k] = boff[k] + s[t] - x;
}

__global__ __launch_bounds__(256) void k_part2(const int* __restrict__ src,
                                               const int* __restrict__ dst,
                                               const float* __restrict__ val,
                                               const int* __restrict__ cnt_pb,
                                               int2* __restrict__ pairs) {
    __shared__ int cnt[NBUCKETS];
    __shared__ int base[NBUCKETS];
    int t = threadIdx.x;
    for (int i = t; i < NBUCKETS; i += 256) {
        base[i] = cnt_pb[blockIdx.x * NBUCKETS + i];
        cnt[i] = 0;
    }
    __syncthreads();
    int e0 = blockIdx.x * CHUNK;
    int e1 = min(e0 + CHUNK, N_EDGES);
    int e = e0 + t;
    for (; e + 7 * 256 < e1; e += 8 * 256) {
        int d_[8], s_[8];
        float v_[8];
#pragma unroll
        for (int j = 0; j < 8; ++j)
            d_[j] = __builtin_nontemporal_load(dst + e + j * 256);
#pragma unroll
        for (int j = 0; j < 8; ++j)
            s_[j] = __builtin_nontemporal_load(src + e + j * 256);
#pragma unroll
        for (int j = 0; j < 8; ++j)
            v_[j] = __builtin_nontemporal_load(val + e + j * 256);
#pragma unroll
        for (int j = 0; j < 8; ++j) {
            int b_ = d_[j] >> 8;
            int o = atomicAdd(&cnt[b_], 1);
            pairs[base[b_] + o] = make_int2(s_[j] | ((d_[j] & 255) << 18),
                                            __float_as_int(v_[j]));
        }
    }
    for (; e < e1; e += 256) {
        int d0 = __builtin_nontemporal_load(dst + e);
        int s0 = __builtin_nontemporal_load(src + e);
        float v0 = __builtin_nontemporal_load(val + e);
        int b_ = d0 >> 8;
        int o0 = atomicAdd(&cnt[b_], 1);
        pairs[base[b_] + o0] = make_int2(s0 | ((d0 & 255) << 18),
                                         __float_as_int(v0));
    }
}

__global__ __launch_bounds__(512) void k_sort(const int* __restrict__ boff,
                                              const int2* __restrict__ pairs1,
                                              int2* __restrict__ pairs2,
                                              int* __restrict__ row_ptr) {
    __shared__ int cnt[ROWS_PER_B];
    __shared__ int s[ROWS_PER_B];
    int b = blockIdx.x;
    int t = threadIdx.x;
    if (t < ROWS_PER_B) cnt[t] = 0;
    __syncthreads();
    int beg = boff[b], end = boff[b + 1];
    {
        int e = beg + t;
        for (; e + 7 * 512 < end; e += 8 * 512) {
            int r_[8];
#pragma unroll
            for (int j = 0; j < 8; ++j)
                r_[j] = ((unsigned)pairs1[e + j * 512].x) >> 18;
#pragma unroll
            for (int j = 0; j < 8; ++j) atomicAdd(&cnt[r_[j]], 1);
        }
        for (; e < end; e += 512)
            atomicAdd(&cnt[((unsigned)pairs1[e].x) >> 18], 1);
    }
    __syncthreads();
    int x = (t < ROWS_PER_B) ? cnt[t] : 0;
    if (t < ROWS_PER_B) s[t] = x;
    __syncthreads();
    for (int off = 1; off < ROWS_PER_B; off <<= 1) {
        int v = (t >= off && t < ROWS_PER_B) ? s[t - off] : 0;
        __syncthreads();
        if (t < ROWS_PER_B) s[t] += v;
        __syncthreads();
    }
    if (t < ROWS_PER_B) {
        int ex = beg + s[t] - x;
        row_ptr[b * ROWS_PER_B + t] = ex;
        cnt[t] = ex;
    }
    if (b == NBUCKETS - 1 && t == 0) row_ptr[NROWS_PAD] = N_EDGES;
    __syncthreads();
    const long* p1l = (const long*)pairs1;
    {
        int e = beg + t;
        for (; e + 7 * 512 < end; e += 8 * 512) {
            long q[8];
#pragma unroll
            for (int j = 0; j < 8; ++j)
                q[j] = __builtin_nontemporal_load(p1l + e + j * 512);
#pragma unroll
            for (int j = 0; j < 8; ++j) {
                int x0 = (int)q[j], y0 = (int)(q[j] >> 32);
                int pos = atomicAdd(&cnt[((unsigned)x0) >> 18], 1);
                pairs2[pos] = make_int2(x0 & 0x3FFFF, y0);
            }
        }
        for (; e < end; e += 512) {
            long q0 = __builtin_nontemporal_load(p1l + e);
            int x0 = (int)q0, y0 = (int)(q0 >> 32);
            int pos = atomicAdd(&cnt[((unsigned)x0) >> 18], 1);
            pairs2[pos] = make_int2(x0 & 0x3FFFF, y0);
        }
    }
}

// ---------------- phase 3: propagation ----------------

__global__ void k_init(const f4v* __restrict__ ue, const f4v* __restrict__ ie,
                       ushort4* __restrict__ e0b, f4v* __restrict__ acc) {
    int i = blockIdx.x * blockDim.x + threadIdx.x;
    if (i >= NODE_F4) return;
    f4v v = (i < USER_F4) ? __builtin_nontemporal_load(ue + i)
                          : __builtin_nontemporal_load(ie + i - USER_F4);
    __builtin_nontemporal_store(v, acc + i);     // re-read only in the final layer
    e0b[i] = make_ushort4(f2bf(v.x), f2bf(v.y), f2bf(v.z), f2bf(v.w));
}

// 16 lanes/row; lane owns 4 channels (8B ushort4 gather). Unroll-8. Streams
// (pairs in, nxt out) are NT so the 4MB L2s hold the cur gather table.
__global__ __launch_bounds__(256) void k_spmm(const int* __restrict__ row_ptr,
                                              const long* __restrict__ pairs,
                                              const ushort4* __restrict__ cur,
                                              ushort4* __restrict__ nxt) {
    int tid = blockIdx.x * blockDim.x + threadIdx.x;
    int row = tid >> 4;
    if (row >= N_NODES) return;
    int c = tid & 15;
    int beg = row_ptr[row];
    int end = row_ptr[row + 1];
    float4 r = make_float4(0.f, 0.f, 0.f, 0.f);
    int k = beg;
    for (; k + 7 < end; k += 8) {
        long p[8];
        ushort4 g[8];
#pragma unroll
        for (int j = 0; j < 8; ++j) p[j] = __builtin_nontemporal_load(pairs + k + j);
#pragma unroll
        for (int j = 0; j < 8; ++j) g[j] = cur[(long)(int)(p[j] & 0x3FFFF) * 16 + c];
#pragma unroll
        for (int j = 0; j < 8; ++j) {
            float v = __int_as_float((int)(p[j] >> 32));
            r.x += v * bf2f(g[j].x);
            r.y += v * bf2f(g[j].y);
            r.z += v * bf2f(g[j].z);
            r.w += v * bf2f(g[j].w);
        }
    }
    for (; k < end; ++k) {
        long p0 = __builtin_nontemporal_load(pairs + k);
        ushort4 g0 = cur[(long)(int)(p0 & 0x3FFFF) * 16 + c];
        float v0 = __int_as_float((int)(p0 >> 32));
        r.x += v0 * bf2f(g0.x);
        r.y += v0 * bf2f(g0.y);
        r.z += v0 * bf2f(g0.z);
        r.w += v0 * bf2f(g0.w);
    }
    unsigned long long o4 = (unsigned long long)f2bf(r.x)
                          | ((unsigned long long)f2bf(r.y) << 16)
                          | ((unsigned long long)f2bf(r.z) << 32)
                          | ((unsigned long long)f2bf(r.w) << 48);
    __builtin_nontemporal_store(o4, (unsigned long long*)(nxt + (long)row * 16 + c));
}

// Final layer: r = SpMM(e2); acc = (acc + e1 + e2 + r) * 0.25
__global__ __launch_bounds__(256) void k_spmm_fin(const int* __restrict__ row_ptr,
                                                  const long* __restrict__ pairs,
                                                  const ushort4* __restrict__ cur,  // e2b
                                                  const ushort4* __restrict__ e1b,
                                                  f4v* __restrict__ acc) {
    int tid = blockIdx.x * blockDim.x + threadIdx.x;
    int row = tid >> 4;
    if (row >= N_NODES) return;
    int c = tid & 15;
    int beg = row_ptr[row];
    int end = row_ptr[row + 1];
    float4 r = make_float4(0.f, 0.f, 0.f, 0.f);
    int k = beg;
    for (; k + 7 < end; k += 8) {
        long p[8];
        ushort4 g[8];
#pragma unroll
        for (int j = 0; j < 8; ++j) p[j] = __builtin_nontemporal_load(pairs + k + j);
#pragma unroll
        for (int j = 0; j < 8; ++j) g[j] = cur[(long)(int)(p[j] & 0x3FFFF) * 16 + c];
#pragma unroll
        for (int j = 0; j < 8; ++j) {
            float v = __int_as_float((int)(p[j] >> 32));
            r.x += v * bf2f(g[j].x);
            r.y += v * bf2f(g[j].y);
            r.z += v * bf2f(g[j].z);
            r.w += v * bf2f(g[j].w);
        }
    }
    for (; k < end; ++k) {
        long p0 = __builtin_nontemporal_load(pairs + k);
        ushort4 g0 = cur[(long)(int)(p0 & 0x3FFFF) * 16 + c];
        float v0 = __int_as_float((int)(p0 >> 32));
        r.x += v0 * bf2f(g0.x);
        r.y += v0 * bf2f(g0.y);
        r.z += v0 * bf2f(g0.z);
        r.w += v0 * bf2f(g0.w);
    }
    long o = (long)row * 16 + c;
    unsigned long long e1q =
        __builtin_nontemporal_load((const unsigned long long*)(e1b + o));
    ushort4 e2 = cur[o];
    f4v a = __builtin_nontemporal_load(acc + o);
    a.x = (a.x + bf2f((unsigned short)(e1q      )) + bf2f(e2.x) + r.x) * 0.25f;
    a.y = (a.y + bf2f((unsigned short)(e1q >> 16)) + bf2f(e2.y) + r.y) * 0.25f;
    a.z = (a.z + bf2f((unsigned short)(e1q >> 32)) + bf2f(e2.z) + r.z) * 0.25f;
    a.w = (a.w + bf2f((unsigned short)(e1q >> 48)) + bf2f(e2.w) + r.w) * 0.25f;
    __builtin_nontemporal_store(a, acc + o);
}

// ---------------- R0 fallback (atomic scatter) for small ws ----------------

__global__ void lgcn_init(const float4* __restrict__ user_emb,
                          const float4* __restrict__ item_emb,
                          float4* __restrict__ cur, float4* __restrict__ nxt,
                          float4* __restrict__ acc) {
    int i = blockIdx.x * blockDim.x + threadIdx.x;
    if (i >= NODE_F4) return;
    float4 v = (i < USER_F4) ? user_emb[i] : item_emb[i - USER_F4];
    cur[i] = v; acc[i] = v; nxt[i] = make_float4(0.f, 0.f, 0.f, 0.f);
}

__global__ void lgcn_scatter(const int* __restrict__ src, const int* __restrict__ dst,
                             const float* __restrict__ val,
                             const float4* __restrict__ cur, float* __restrict__ nxt) {
    int tid = blockIdx.x * blockDim.x + threadIdx.x;
    int e = tid >> 4;
    if (e >= N_EDGES) return;
    int c = tid & 15;
    int s = src[e]; int d = dst[e]; float v = val[e];
    float4 m = cur[(long)s * 16 + c];
    float* p = nxt + (long)d * 64 + c * 4;
    unsafeAtomicAdd(p + 0, v * m.x);
    unsafeAtomicAdd(p + 1, v * m.y);
    unsafeAtomicAdd(p + 2, v * m.z);
    unsafeAtomicAdd(p + 3, v * m.w);
}

__global__ void lgcn_add_zero(float4* __restrict__ acc, const float4* __restrict__ nxt,
                              float4* __restrict__ other) {
    int i = blockIdx.x * blockDim.x + threadIdx.x;
    if (i >= NODE_F4) return;
    float4 a = acc[i]; float4 n = nxt[i];
    a.x += n.x; a.y += n.y; a.z += n.z; a.w += n.w;
    acc[i] = a;
    other[i] = make_float4(0.f, 0.f, 0.f, 0.f);
}

__global__ void lgcn_final(float4* __restrict__ acc, const float4* __restrict__ nxt) {
    int i = blockIdx.x * blockDim.x + threadIdx.x;
    if (i >= NODE_F4) return;
    float4 a = acc[i]; float4 n = nxt[i];
    a.x = (a.x + n.x) * 0.25f; a.y = (a.y + n.y) * 0.25f;
    a.z = (a.z + n.z) * 0.25f; a.w = (a.w + n.w) * 0.25f;
    acc[i] = a;
}

// ---------------- launch ----------------

extern "C" void kernel_launch(void* const* d_in, const int* in_sizes, int n_in,
                              void* d_out, int out_size, void* d_ws, size_t ws_size,
                              hipStream_t stream) {
    const int*    adj_src  = (const int*)d_in[2];
    const int*    adj_dst  = (const int*)d_in[3];
    const float*  adj_vals = (const float*)d_in[4];
    float* acc = (float*)d_out;

    const int BLK = 256;
    const int grid_node  = (NODE_F4 + BLK - 1) / BLK;        // 9375
    const int grid_row16 = (N_NODES * 16 + BLK - 1) / BLK;   // 9375

    const size_t SZ_PAIRS = (size_t)N_EDGES * 8;             // 48,000,000
    const size_t SZ_P1PAD = (size_t)NBUCKETS * CAP_B * 8;    // 51,342,976
    const size_t SZ_BF    = (size_t)N_NODES * EMB * 2;       // 19,200,000
    const size_t SZ_RP    = 600320;                          // 150017 ints, padded
    const size_t SZ_B     = 4096;
    const size_t NEEDED1  = SZ_PAIRS + SZ_P1PAD + SZ_BF + SZ_RP + 2 * SZ_B;  // ~119.2 MB
    const size_t NEEDED2  = 2 * SZ_PAIRS + SZ_BF + SZ_RP + 3 * SZ_B;         // ~115.8 MB

    if (ws_size >= NEEDED1) {
        // ---- tier 1: padded buckets, no pre-count pipeline ----
        // [0,48M) pairs2 | [48M, +51.3M) pairs1_pad (e0b/e1b alias) |
        // [99.3M, +19.2M) e2b | row_ptr | gcur | boff
        char* w = (char*)d_ws;
        int2*    pairs2 = (int2*)(w);
        int2*    pairs1 = (int2*)(w + SZ_PAIRS);
        ushort4* e0b    = (ushort4*)(w + SZ_PAIRS);            // aliases pairs1
        ushort4* e1b    = (ushort4*)(w + SZ_PAIRS + SZ_BF);    // aliases pairs1
        ushort4* e2b    = (ushort4*)(w + SZ_PAIRS + SZ_P1PAD);
        int*  row_ptr= (int*)(w + SZ_PAIRS + SZ_P1PAD + SZ_BF);
        int*  gcur   = (int*)(w + SZ_PAIRS + SZ_P1PAD + SZ_BF + SZ_RP);
        int*  boff   = (int*)(w + SZ_PAIRS + SZ_P1PAD + SZ_BF + SZ_RP + SZ_B);

        k_ginit<<<(NBUCKETS + BLK - 1) / BLK, BLK, 0, stream>>>(gcur);
        k_part<<<PART_BLOCKS, BLK, 0, stream>>>(adj_src, adj_dst, adj_vals,
                                                gcur, pairs1);
        k_fill<<<1, 1024, 0, stream>>>(gcur, boff);
        k_sortA<<<NBUCKETS, 1024, 0, stream>>>(gcur, boff, pairs1, pairs2, row_ptr);

        k_init<<<grid_node, BLK, 0, stream>>>((const f4v*)d_in[5], (const f4v*)d_in[6],
                                              e0b, (f4v*)acc);
        k_spmm<<<grid_row16, BLK, 0, stream>>>(row_ptr, (const long*)pairs2, e0b, e1b);
        k_spmm<<<grid_row16, BLK, 0, stream>>>(row_ptr, (const long*)pairs2, e1b, e2b);
        k_spmm_fin<<<grid_row16, BLK, 0, stream>>>(row_ptr, (const long*)pairs2, e2b,
                                                   e1b, (f4v*)acc);
    } else if (ws_size >= NEEDED2) {
        // ---- tier 2: R12 exact path ----
        char* w = (char*)d_ws;
        int2*    pairs2 = (int2*)(w);
        int*     cnt_pb = (int*)(w);                          // aliases pairs2 head
        int2*    pairs1 = (int2*)(w + SZ_PAIRS);
        ushort4* e0b    = (ushort4*)(w + SZ_PAIRS);           // aliases pairs1
        ushort4* e1b    = (ushort4*)(w + SZ_PAIRS + SZ_BF);   // aliases pairs1
        ushort4* e2b    = (ushort4*)(w + 2 * SZ_PAIRS);
        int*  row_ptr= (int*)(w + 2 * SZ_PAIRS + SZ_BF);
        int*  gcnt   = (int*)(w + 2 * SZ_PAIRS + SZ_BF + SZ_RP);
        int*  boff   = (int*)(w + 2 * SZ_PAIRS + SZ_BF + SZ_RP + SZ_B);

        k_zero<<<(NBUCKETS + BLK - 1) / BLK, BLK, 0, stream>>>(gcnt, NBUCKETS);
        k_bhist<<<PART_BLOCKS, BLK, 0, stream>>>(adj_dst, gcnt, cnt_pb);
        k_bscan<<<1, 1024, 0, stream>>>(gcnt, boff);
        k_pscan<<<NBUCKETS, PART_BLOCKS, 0, stream>>>(boff, cnt_pb);
        k_part2<<<PART_BLOCKS, BLK, 0, stream>>>(adj_src, adj_dst, adj_vals,
                                                 cnt_pb, pairs1);
        k_sort<<<NBUCKETS, 512, 0, stream>>>(boff, pairs1, pairs2, row_ptr);

        k_init<<<grid_node, BLK, 0, stream>>>((const f4v*)d_in[5], (const f4v*)d_in[6],
                                              e0b, (f4v*)acc);
        k_spmm<<<grid_row16, BLK, 0, stream>>>(row_ptr, (const long*)pairs2, e0b, e1b);
        k_spmm<<<grid_row16, BLK, 0, stream>>>(row_ptr, (const long*)pairs2, e1b, e2b);
        k_spmm_fin<<<grid_row16, BLK, 0, stream>>>(row_ptr, (const long*)pairs2, e2b,
                                                   e1b, (f4v*)acc);
    } else {
        // ---- tier 3: R0 fallback ----
        const float4* user_emb = (const float4*)d_in[5];
        const float4* item_emb = (const float4*)d_in[6];
        float* ws0 = (float*)d_ws;
        float* ws1 = ws0 + (size_t)N_NODES * EMB;
        lgcn_init<<<grid_node, BLK, 0, stream>>>(user_emb, item_emb,
                                                 (float4*)ws0, (float4*)ws1, (float4*)acc);
        lgcn_scatter<<<(N_EDGES*16+BLK-1)/BLK, BLK, 0, stream>>>(adj_src, adj_dst, adj_vals,
                                                    (const float4*)ws0, ws1);
        lgcn_add_zero<<<grid_node, BLK, 0, stream>>>((float4*)acc, (const float4*)ws1, (float4*)ws0);
        lgcn_scatter<<<(N_EDGES*16+BLK-1)/BLK, BLK, 0, stream>>>(adj_src, adj_dst, adj_vals,
                                                    (const float4*)ws1, ws0);
        lgcn_add_zero<<<grid_node, BLK, 0, stream>>>((float4*)acc, (const float4*)ws0, (float4*)ws1);
        lgcn_scatter<<<(N_EDGES*16+BLK-1)/BLK, BLK, 0, stream>>>(adj_src, adj_dst, adj_vals,
                                                    (const float4*)ws0, ws1);
        lgcn_final<<<grid_node, BLK, 0, stream>>>((float4*)acc, (const float4*)ws1);
    }
}

// Round 9
// 592.936 us; speedup vs baseline: 1.1308x; 1.1308x over previous
//
#include <hip/hip_runtime.h>

// LightGCN propagation on MI355X — R17: R13 base with 512-bucket geometry
// (kills k_sortA's 2-round tail) + k_init/k_spmm_fin acc fusion.
//
// R16 post-mortem: NT pair loads REGRESSED (607->670, FETCH 384->427MB):
// pairs words are broadcast across 16 lanes + shared across adjacent rows;
// L2 served that reuse, NT defeated it. Three falsifications now agree the
// spmm is L2-miss-service bound at its achievable traffic floor (~430MB/layer;
// col-blocking arithmetic is a wash). spmm reverted to R13 form, frozen.
//
// R17: k_sortA ran 586 blocks x 16 waves with a 512-block concurrency limit
// (2 blocks/CU) -> 2 sequential rounds, 57% slot utilization. New geometry:
// NBUCKETS=512, ROWS_PER_B=293 (512*293=150016), bucket=dst/293 (magic div,
// k_part VALU was 1.6%), 9-bit local row packed at bit 18. CAP_B=12480
// (mean 11719 + 7sigma). k_sortA now exactly 1 round.
// Also: k_init no longer writes acc (-38.4MB); k_spmm_fin reads user/item
// emb f32 directly (bit-identical e0). Tier-2 deleted (tier-1 always ran).
//
// Inputs: [2] adj_src (6M int), [3] adj_dst (6M int), [4] adj_vals (6M f32),
//         [5] user_emb (100000x64 f32), [6] item_emb (50000x64 f32).
// Output: [150000x64] f32 = (e0+e1+e2+e3)/4.

#define NUM_USERS 100000
#define NUM_ITEMS 50000
#define N_NODES   150000
#define EMB       64
#define N_EDGES   6000000

#define RPB       293                         // rows per bucket
#define NBUCKETS  512
#define NROWS_PAD (NBUCKETS * RPB)            // 150016
#define PART_BLOCKS 512
#define CHUNK ((N_EDGES + PART_BLOCKS - 1) / PART_BLOCKS)   // 11719
#define CAP_B 12480                           // 11719 + 7 sigma, padded bucket cap

constexpr int NODE_F4 = N_NODES * EMB / 4;   // 2,400,000
constexpr int USER_F4 = NUM_USERS * EMB / 4; // 1,600,000

typedef float f4v __attribute__((ext_vector_type(4)));   // 16B clang vector

__device__ __forceinline__ float bf2f(unsigned short u) {
    union { unsigned int i; float f; } x; x.i = ((unsigned int)u) << 16; return x.f;
}
__device__ __forceinline__ unsigned short f2bf(float f) {
    union { float f; unsigned int i; } x; x.f = f;
    unsigned int b = x.i;
    return (unsigned short)((b + 0x7FFFu + ((b >> 16) & 1u)) >> 16);  // RNE
}

// ================= tier-1 (padded-bucket) kernels =================

__global__ void k_ginit(int* __restrict__ gcur) {
    int i = blockIdx.x * blockDim.x + threadIdx.x;
    if (i < NBUCKETS) gcur[i] = i * CAP_B;
}

// self-count + claim + scatter; bases claimed from gcur pre-set to k*CAP.
// entry: x = src | (dstLocal<<18)  (src 18b, local 9b), y = val bits.
__global__ __launch_bounds__(256) void k_part(const int* __restrict__ src,
                                              const int* __restrict__ dst,
                                              const float* __restrict__ val,
                                              int* __restrict__ gcur,
                                              int2* __restrict__ pairs) {
    __shared__ int cnt[NBUCKETS];
    __shared__ int base[NBUCKETS];
    int t = threadIdx.x;
    for (int i = t; i < NBUCKETS; i += 256) cnt[i] = 0;
    __syncthreads();
    int e0 = blockIdx.x * CHUNK;
    int e1 = min(e0 + CHUNK, N_EDGES);
    {
        int e = e0 + t;
        for (; e + 7 * 256 < e1; e += 8 * 256) {
            int b_[8];
#pragma unroll
            for (int j = 0; j < 8; ++j)
                b_[j] = (int)((unsigned)__builtin_nontemporal_load(dst + e + j * 256) / (unsigned)RPB);
#pragma unroll
            for (int j = 0; j < 8; ++j) atomicAdd(&cnt[b_[j]], 1);
        }
        for (; e < e1; e += 256)
            atomicAdd(&cnt[(unsigned)__builtin_nontemporal_load(dst + e) / (unsigned)RPB], 1);
    }
    __syncthreads();
    for (int i = t; i < NBUCKETS; i += 256) {
        int c = cnt[i];
        base[i] = c ? atomicAdd(&gcur[i], c) : 0;
        cnt[i] = 0;
    }
    __syncthreads();
    {
        int e = e0 + t;
        for (; e + 7 * 256 < e1; e += 8 * 256) {
            int d_[8], s_[8];
            float v_[8];
#pragma unroll
            for (int j = 0; j < 8; ++j)
                d_[j] = __builtin_nontemporal_load(dst + e + j * 256);
#pragma unroll
            for (int j = 0; j < 8; ++j)
                s_[j] = __builtin_nontemporal_load(src + e + j * 256);
#pragma unroll
            for (int j = 0; j < 8; ++j)
                v_[j] = __builtin_nontemporal_load(val + e + j * 256);
#pragma unroll
            for (int j = 0; j < 8; ++j) {
                int b_ = (int)((unsigned)d_[j] / (unsigned)RPB);
                int lo = d_[j] - b_ * RPB;
                int o = atomicAdd(&cnt[b_], 1);
                pairs[base[b_] + o] = make_int2(s_[j] | (lo << 18),
                                                __float_as_int(v_[j]));
            }
        }
        for (; e < e1; e += 256) {
            int d0 = __builtin_nontemporal_load(dst + e);
            int s0 = __builtin_nontemporal_load(src + e);
            float v0 = __builtin_nontemporal_load(val + e);
            int b_ = (int)((unsigned)d0 / (unsigned)RPB);
            int lo = d0 - b_ * RPB;
            int o0 = atomicAdd(&cnt[b_], 1);
            pairs[base[b_] + o0] = make_int2(s0 | (lo << 18),
                                             __float_as_int(v0));
        }
    }
}

// fills = gcur[k] - k*CAP -> exclusive scan -> exact dense bucket offsets
__global__ void k_fill(const int* __restrict__ gcur, int* __restrict__ boff) {
    __shared__ int s[1024];
    int t = threadIdx.x;
    int x = (t < NBUCKETS) ? (gcur[t] - t * CAP_B) : 0;
    s[t] = x;
    __syncthreads();
    for (int off = 1; off < 1024; off <<= 1) {
        int v = (t >= off) ? s[t - off] : 0;
        __syncthreads();
        s[t] += v;
        __syncthreads();
    }
    if (t < NBUCKETS) boff[t] = s[t] - x;
    if (t == 0) boff[NBUCKETS] = N_EDGES;
}

// per-bucket row sort from padded source range; 512 blocks x 1024 threads
// = exactly 2 blocks/CU (32 waves) -> single scheduling round.
__global__ __launch_bounds__(1024) void k_sortA(const int* __restrict__ gcur,
                                                const int* __restrict__ boff,
                                                const int2* __restrict__ pairs1,
                                                int2* __restrict__ pairs2,
                                                int* __restrict__ row_ptr) {
    __shared__ int cnt[RPB];    // counts, then cursors
    __shared__ int s[RPB];
    int b = blockIdx.x;
    int t = threadIdx.x;
    if (t < RPB) cnt[t] = 0;
    __syncthreads();
    int beg = b * CAP_B;
    int end = gcur[b];
    {
        int e = beg + t;
        for (; e + 7 * 1024 < end; e += 8 * 1024) {
            int r_[8];
#pragma unroll
            for (int j = 0; j < 8; ++j)
                r_[j] = ((unsigned)pairs1[e + j * 1024].x) >> 18;  // cached: reused by pass 2
#pragma unroll
            for (int j = 0; j < 8; ++j) atomicAdd(&cnt[r_[j]], 1);
        }
        for (; e < end; e += 1024)
            atomicAdd(&cnt[((unsigned)pairs1[e].x) >> 18], 1);
    }
    __syncthreads();
    int x = (t < RPB) ? cnt[t] : 0;
    if (t < RPB) s[t] = x;
    __syncthreads();
    for (int off = 1; off < RPB; off <<= 1) {
        int v = (t >= off && t < RPB) ? s[t - off] : 0;
        __syncthreads();
        if (t < RPB) s[t] += v;
        __syncthreads();
    }
    if (t < RPB) {
        int ex = boff[b] + s[t] - x;
        row_ptr[b * RPB + t] = ex;
        cnt[t] = ex;
    }
    if (b == NBUCKETS - 1 && t == 0) row_ptr[NROWS_PAD] = N_EDGES;
    __syncthreads();
    const long* p1l = (const long*)pairs1;
    {
        int e = beg + t;
        for (; e + 7 * 1024 < end; e += 8 * 1024) {
            long q[8];
#pragma unroll
            for (int j = 0; j < 8; ++j)
                q[j] = __builtin_nontemporal_load(p1l + e + j * 1024);  // last read: NT
#pragma unroll
            for (int j = 0; j < 8; ++j) {
                int x0 = (int)q[j], y0 = (int)(q[j] >> 32);
                int pos = atomicAdd(&cnt[((unsigned)x0) >> 18], 1);
                pairs2[pos] = make_int2(x0 & 0x3FFFF, y0);
            }
        }
        for (; e < end; e += 1024) {
            long q0 = __builtin_nontemporal_load(p1l + e);
            int x0 = (int)q0, y0 = (int)(q0 >> 32);
            int pos = atomicAdd(&cnt[((unsigned)x0) >> 18], 1);
            pairs2[pos] = make_int2(x0 & 0x3FFFF, y0);
        }
    }
}

// ---------------- phase 3: propagation ----------------

// e0b only; acc is no longer materialized (k_spmm_fin reads embs directly).
__global__ void k_init(const f4v* __restrict__ ue, const f4v* __restrict__ ie,
                       ushort4* __restrict__ e0b) {
    int i = blockIdx.x * blockDim.x + threadIdx.x;
    if (i >= NODE_F4) return;
    f4v v = (i < USER_F4) ? __builtin_nontemporal_load(ue + i)
                          : __builtin_nontemporal_load(ie + i - USER_F4);
    e0b[i] = make_ushort4(f2bf(v.x), f2bf(v.y), f2bf(v.z), f2bf(v.w));
}

// 16 lanes/row; lane owns 4 channels (8B ushort4 gather). Unroll-8 (R13 form,
// frozen: divergence fix / masked tail / NT all measured worse).
__global__ __launch_bounds__(256) void k_spmm(const int* __restrict__ row_ptr,
                                              const long* __restrict__ pairs,
                                              const ushort4* __restrict__ cur,
                                              ushort4* __restrict__ nxt) {
    int tid = blockIdx.x * blockDim.x + threadIdx.x;
    int row = tid >> 4;
    if (row >= N_NODES) return;
    int c = tid & 15;
    int beg = row_ptr[row];
    int end = row_ptr[row + 1];
    float4 r = make_float4(0.f, 0.f, 0.f, 0.f);
    int k = beg;
    for (; k + 7 < end; k += 8) {
        long p[8];
        ushort4 g[8];
#pragma unroll
        for (int j = 0; j < 8; ++j) p[j] = pairs[k + j];
#pragma unroll
        for (int j = 0; j < 8; ++j) g[j] = cur[(long)(int)(p[j] & 0x3FFFF) * 16 + c];
#pragma unroll
        for (int j = 0; j < 8; ++j) {
            float v = __int_as_float((int)(p[j] >> 32));
            r.x += v * bf2f(g[j].x);
            r.y += v * bf2f(g[j].y);
            r.z += v * bf2f(g[j].z);
            r.w += v * bf2f(g[j].w);
        }
    }
    for (; k < end; ++k) {
        long p0 = pairs[k];
        ushort4 g0 = cur[(long)(int)(p0 & 0x3FFFF) * 16 + c];
        float v0 = __int_as_float((int)(p0 >> 32));
        r.x += v0 * bf2f(g0.x);
        r.y += v0 * bf2f(g0.y);
        r.z += v0 * bf2f(g0.z);
        r.w += v0 * bf2f(g0.w);
    }
    nxt[(long)row * 16 + c] = make_ushort4(f2bf(r.x), f2bf(r.y), f2bf(r.z), f2bf(r.w));
}

// Final layer: r = SpMM(e2); acc_out = (e0 + e1 + e2 + r) * 0.25,
// with e0 read straight from the f32 embeddings (bit-identical to old acc).
__global__ __launch_bounds__(256) void k_spmm_fin(const int* __restrict__ row_ptr,
                                                  const long* __restrict__ pairs,
                                                  const ushort4* __restrict__ cur,  // e2b
                                                  const ushort4* __restrict__ e1b,
                                                  const f4v* __restrict__ ue,
                                                  const f4v* __restrict__ ie,
                                                  float4* __restrict__ acc) {
    int tid = blockIdx.x * blockDim.x + threadIdx.x;
    int row = tid >> 4;
    if (row >= N_NODES) return;
    int c = tid & 15;
    int beg = row_ptr[row];
    int end = row_ptr[row + 1];
    float4 r = make_float4(0.f, 0.f, 0.f, 0.f);
    int k = beg;
    for (; k + 7 < end; k += 8) {
        long p[8];
        ushort4 g[8];
#pragma unroll
        for (int j = 0; j < 8; ++j) p[j] = pairs[k + j];
#pragma unroll
        for (int j = 0; j < 8; ++j) g[j] = cur[(long)(int)(p[j] & 0x3FFFF) * 16 + c];
#pragma unroll
        for (int j = 0; j < 8; ++j) {
            float v = __int_as_float((int)(p[j] >> 32));
            r.x += v * bf2f(g[j].x);
            r.y += v * bf2f(g[j].y);
            r.z += v * bf2f(g[j].z);
            r.w += v * bf2f(g[j].w);
        }
    }
    for (; k < end; ++k) {
        long p0 = pairs[k];
        ushort4 g0 = cur[(long)(int)(p0 & 0x3FFFF) * 16 + c];
        float v0 = __int_as_float((int)(p0 >> 32));
        r.x += v0 * bf2f(g0.x);
        r.y += v0 * bf2f(g0.y);
        r.z += v0 * bf2f(g0.z);
        r.w += v0 * bf2f(g0.w);
    }
    long o = (long)row * 16 + c;
    f4v e0 = (row < NUM_USERS) ? ue[o] : ie[o - (long)NUM_USERS * 16];
    ushort4 e1 = e1b[o];
    ushort4 e2 = cur[o];
    float4 a;
    a.x = (e0.x + bf2f(e1.x) + bf2f(e2.x) + r.x) * 0.25f;
    a.y = (e0.y + bf2f(e1.y) + bf2f(e2.y) + r.y) * 0.25f;
    a.z = (e0.z + bf2f(e1.z) + bf2f(e2.z) + r.z) * 0.25f;
    a.w = (e0.w + bf2f(e1.w) + bf2f(e2.w) + r.w) * 0.25f;
    acc[o] = a;
}

// ---------------- R0 fallback (atomic scatter) for small ws ----------------

__global__ void lgcn_init(const float4* __restrict__ user_emb,
                          const float4* __restrict__ item_emb,
                          float4* __restrict__ cur, float4* __restrict__ nxt,
                          float4* __restrict__ acc) {
    int i = blockIdx.x * blockDim.x + threadIdx.x;
    if (i >= NODE_F4) return;
    float4 v = (i < USER_F4) ? user_emb[i] : item_emb[i - USER_F4];
    cur[i] = v; acc[i] = v; nxt[i] = make_float4(0.f, 0.f, 0.f, 0.f);
}

__global__ void lgcn_scatter(const int* __restrict__ src, const int* __restrict__ dst,
                             const float* __restrict__ val,
                             const float4* __restrict__ cur, float* __restrict__ nxt) {
    int tid = blockIdx.x * blockDim.x + threadIdx.x;
    int e = tid >> 4;
    if (e >= N_EDGES) return;
    int c = tid & 15;
    int s = src[e]; int d = dst[e]; float v = val[e];
    float4 m = cur[(long)s * 16 + c];
    float* p = nxt + (long)d * 64 + c * 4;
    unsafeAtomicAdd(p + 0, v * m.x);
    unsafeAtomicAdd(p + 1, v * m.y);
    unsafeAtomicAdd(p + 2, v * m.z);
    unsafeAtomicAdd(p + 3, v * m.w);
}

__global__ void lgcn_add_zero(float4* __restrict__ acc, const float4* __restrict__ nxt,
                              float4* __restrict__ other) {
    int i = blockIdx.x * blockDim.x + threadIdx.x;
    if (i >= NODE_F4) return;
    float4 a = acc[i]; float4 n = nxt[i];
    a.x += n.x; a.y += n.y; a.z += n.z; a.w += n.w;
    acc[i] = a;
    other[i] = make_float4(0.f, 0.f, 0.f, 0.f);
}

__global__ void lgcn_final(float4* __restrict__ acc, const float4* __restrict__ nxt) {
    int i = blockIdx.x * blockDim.x + threadIdx.x;
    if (i >= NODE_F4) return;
    float4 a = acc[i]; float4 n = nxt[i];
    a.x = (a.x + n.x) * 0.25f; a.y = (a.y + n.y) * 0.25f;
    a.z = (a.z + n.z) * 0.25f; a.w = (a.w + n.w) * 0.25f;
    acc[i] = a;
}

// ---------------- launch ----------------

extern "C" void kernel_launch(void* const* d_in, const int* in_sizes, int n_in,
                              void* d_out, int out_size, void* d_ws, size_t ws_size,
                              hipStream_t stream) {
    const int*    adj_src  = (const int*)d_in[2];
    const int*    adj_dst  = (const int*)d_in[3];
    const float*  adj_vals = (const float*)d_in[4];
    float* acc = (float*)d_out;

    const int BLK = 256;
    const int grid_node  = (NODE_F4 + BLK - 1) / BLK;        // 9375
    const int grid_row16 = (N_NODES * 16 + BLK - 1) / BLK;   // 9375

    const size_t SZ_PAIRS = (size_t)N_EDGES * 8;             // 48,000,000
    const size_t SZ_P1PAD = (size_t)NBUCKETS * CAP_B * 8;    // 51,118,080
    const size_t SZ_BF    = (size_t)N_NODES * EMB * 2;       // 19,200,000
    const size_t SZ_RP    = 600320;                          // 150017 ints, padded
    const size_t SZ_B     = 4096;
    const size_t NEEDED1  = SZ_PAIRS + SZ_P1PAD + SZ_BF + SZ_RP + 2 * SZ_B;  // ~118.9 MB

    if (ws_size >= NEEDED1) {
        // ---- tier 1: padded buckets ----
        // [0,48M) pairs2 | [48M, +51.1M) pairs1_pad (e0b/e1b alias) |
        // [99.1M, +19.2M) e2b | row_ptr | gcur | boff
        char* w = (char*)d_ws;
        int2*    pairs2 = (int2*)(w);
        int2*    pairs1 = (int2*)(w + SZ_PAIRS);
        ushort4* e0b    = (ushort4*)(w + SZ_PAIRS);            // aliases pairs1
        ushort4* e1b    = (ushort4*)(w + SZ_PAIRS + SZ_BF);    // aliases pairs1
        ushort4* e2b    = (ushort4*)(w + SZ_PAIRS + SZ_P1PAD);
        int*  row_ptr= (int*)(w + SZ_PAIRS + SZ_P1PAD + SZ_BF);
        int*  gcur   = (int*)(w + SZ_PAIRS + SZ_P1PAD + SZ_BF + SZ_RP);
        int*  boff   = (int*)(w + SZ_PAIRS + SZ_P1PAD + SZ_BF + SZ_RP + SZ_B);

        k_ginit<<<(NBUCKETS + BLK - 1) / BLK, BLK, 0, stream>>>(gcur);
        k_part<<<PART_BLOCKS, BLK, 0, stream>>>(adj_src, adj_dst, adj_vals,
                                                gcur, pairs1);
        k_fill<<<1, 1024, 0, stream>>>(gcur, boff);
        k_sortA<<<NBUCKETS, 1024, 0, stream>>>(gcur, boff, pairs1, pairs2, row_ptr);

        k_init<<<grid_node, BLK, 0, stream>>>((const f4v*)d_in[5], (const f4v*)d_in[6],
                                              e0b);
        k_spmm<<<grid_row16, BLK, 0, stream>>>(row_ptr, (const long*)pairs2, e0b, e1b);
        k_spmm<<<grid_row16, BLK, 0, stream>>>(row_ptr, (const long*)pairs2, e1b, e2b);
        k_spmm_fin<<<grid_row16, BLK, 0, stream>>>(row_ptr, (const long*)pairs2, e2b,
                                                   e1b, (const f4v*)d_in[5],
                                                   (const f4v*)d_in[6], (float4*)acc);
    } else {
        // ---- fallback: atomic scatter ----
        const float4* user_emb = (const float4*)d_in[5];
        const float4* item_emb = (const float4*)d_in[6];
        float* ws0 = (float*)d_ws;
        float* ws1 = ws0 + (size_t)N_NODES * EMB;
        lgcn_init<<<grid_node, BLK, 0, stream>>>(user_emb, item_emb,
                                                 (float4*)ws0, (float4*)ws1, (float4*)acc);
        lgcn_scatter<<<(N_EDGES*16+BLK-1)/BLK, BLK, 0, stream>>>(adj_src, adj_dst, adj_vals,
                                                    (const float4*)ws0, ws1);
        lgcn_add_zero<<<grid_node, BLK, 0, stream>>>((float4*)acc, (const float4*)ws1, (float4*)ws0);
        lgcn_scatter<<<(N_EDGES*16+BLK-1)/BLK, BLK, 0, stream>>>(adj_src, adj_dst, adj_vals,
                                                    (const float4*)ws1, ws0);
        lgcn_add_zero<<<grid_node, BLK, 0, stream>>>((float4*)acc, (const float4*)ws0, (float4*)ws1);
        lgcn_scatter<<<(N_EDGES*16+BLK-1)/BLK, BLK, 0, stream>>>(adj_src, adj_dst, adj_vals,
                                                    (const float4*)ws0, ws1);
        lgcn_final<<<grid_node, BLK, 0, stream>>>((float4*)acc, (const float4*)ws1);
    }
}

// Round 10
// 592.331 us; speedup vs baseline: 1.1320x; 1.0010x over previous
//
#include <hip/hip_runtime.h>

// LightGCN propagation on MI355X — R18: R17 base + k_part at 1024 threads
// (8->32 waves/CU TLP) + k_sortA pass-1 8-way sub-histograms (LDS atomic
// contention 4.4-way -> ~1.3-way).
//
// R17 post-mortem: 607->593. k_sortA's 2-round tail was worth only ~12us
// (throughput-bound, not slot-bound); k_init fusion ~+6; spmm_fin -3.5
// (e0 f32 reads, covered). Remaining prep cost attributed to LDS atomic
// serialization (6M atomics vs 293 counters) and k_part's 8 waves/CU.
//
// R18 changes are pure TLP/contention knobs, no semantic or layout change:
//  - k_part: same 512 blocks (write runs unchanged), 1024 threads/block.
//  - k_sortA pass 1: cnt8[8][293], thread uses copy t&7, reduce after.
// Pre-commit: <10us total -> prep at floor -> ROOFLINE next round.
//
// Inputs: [2] adj_src (6M int), [3] adj_dst (6M int), [4] adj_vals (6M f32),
//         [5] user_emb (100000x64 f32), [6] item_emb (50000x64 f32).
// Output: [150000x64] f32 = (e0+e1+e2+e3)/4.

#define NUM_USERS 100000
#define NUM_ITEMS 50000
#define N_NODES   150000
#define EMB       64
#define N_EDGES   6000000

#define RPB       293                         // rows per bucket
#define NBUCKETS  512
#define NROWS_PAD (NBUCKETS * RPB)            // 150016
#define PART_BLOCKS 512
#define PTHREADS  1024                        // k_part threads/block (R18)
#define CHUNK ((N_EDGES + PART_BLOCKS - 1) / PART_BLOCKS)   // 11719
#define CAP_B 12480                           // 11719 + 7 sigma, padded bucket cap

constexpr int NODE_F4 = N_NODES * EMB / 4;   // 2,400,000
constexpr int USER_F4 = NUM_USERS * EMB / 4; // 1,600,000

typedef float f4v __attribute__((ext_vector_type(4)));   // 16B clang vector

__device__ __forceinline__ float bf2f(unsigned short u) {
    union { unsigned int i; float f; } x; x.i = ((unsigned int)u) << 16; return x.f;
}
__device__ __forceinline__ unsigned short f2bf(float f) {
    union { float f; unsigned int i; } x; x.f = f;
    unsigned int b = x.i;
    return (unsigned short)((b + 0x7FFFu + ((b >> 16) & 1u)) >> 16);  // RNE
}

// ================= tier-1 (padded-bucket) kernels =================

__global__ void k_ginit(int* __restrict__ gcur) {
    int i = blockIdx.x * blockDim.x + threadIdx.x;
    if (i < NBUCKETS) gcur[i] = i * CAP_B;
}

// self-count + claim + scatter; bases claimed from gcur pre-set to k*CAP.
// entry: x = src | (dstLocal<<18)  (src 18b, local 9b), y = val bits.
// 1024 threads/block x 512 blocks = 2 blocks/CU = 32 waves/CU (was 8).
__global__ __launch_bounds__(PTHREADS) void k_part(const int* __restrict__ src,
                                                   const int* __restrict__ dst,
                                                   const float* __restrict__ val,
                                                   int* __restrict__ gcur,
                                                   int2* __restrict__ pairs) {
    __shared__ int cnt[NBUCKETS];
    __shared__ int base[NBUCKETS];
    int t = threadIdx.x;
    for (int i = t; i < NBUCKETS; i += PTHREADS) cnt[i] = 0;
    __syncthreads();
    int e0 = blockIdx.x * CHUNK;
    int e1 = min(e0 + CHUNK, N_EDGES);
    {
        int e = e0 + t;
        for (; e + 7 * PTHREADS < e1; e += 8 * PTHREADS) {
            int b_[8];
#pragma unroll
            for (int j = 0; j < 8; ++j)
                b_[j] = (int)((unsigned)__builtin_nontemporal_load(dst + e + j * PTHREADS) / (unsigned)RPB);
#pragma unroll
            for (int j = 0; j < 8; ++j) atomicAdd(&cnt[b_[j]], 1);
        }
        for (; e < e1; e += PTHREADS)
            atomicAdd(&cnt[(unsigned)__builtin_nontemporal_load(dst + e) / (unsigned)RPB], 1);
    }
    __syncthreads();
    for (int i = t; i < NBUCKETS; i += PTHREADS) {
        int c = cnt[i];
        base[i] = c ? atomicAdd(&gcur[i], c) : 0;
        cnt[i] = 0;
    }
    __syncthreads();
    {
        int e = e0 + t;
        for (; e + 7 * PTHREADS < e1; e += 8 * PTHREADS) {
            int d_[8], s_[8];
            float v_[8];
#pragma unroll
            for (int j = 0; j < 8; ++j)
                d_[j] = __builtin_nontemporal_load(dst + e + j * PTHREADS);
#pragma unroll
            for (int j = 0; j < 8; ++j)
                s_[j] = __builtin_nontemporal_load(src + e + j * PTHREADS);
#pragma unroll
            for (int j = 0; j < 8; ++j)
                v_[j] = __builtin_nontemporal_load(val + e + j * PTHREADS);
#pragma unroll
            for (int j = 0; j < 8; ++j) {
                int b_ = (int)((unsigned)d_[j] / (unsigned)RPB);
                int lo = d_[j] - b_ * RPB;
                int o = atomicAdd(&cnt[b_], 1);
                pairs[base[b_] + o] = make_int2(s_[j] | (lo << 18),
                                                __float_as_int(v_[j]));
            }
        }
        for (; e < e1; e += PTHREADS) {
            int d0 = __builtin_nontemporal_load(dst + e);
            int s0 = __builtin_nontemporal_load(src + e);
            float v0 = __builtin_nontemporal_load(val + e);
            int b_ = (int)((unsigned)d0 / (unsigned)RPB);
            int lo = d0 - b_ * RPB;
            int o0 = atomicAdd(&cnt[b_], 1);
            pairs[base[b_] + o0] = make_int2(s0 | (lo << 18),
                                             __float_as_int(v0));
        }
    }
}

// fills = gcur[k] - k*CAP -> exclusive scan -> exact dense bucket offsets
__global__ void k_fill(const int* __restrict__ gcur, int* __restrict__ boff) {
    __shared__ int s[1024];
    int t = threadIdx.x;
    int x = (t < NBUCKETS) ? (gcur[t] - t * CAP_B) : 0;
    s[t] = x;
    __syncthreads();
    for (int off = 1; off < 1024; off <<= 1) {
        int v = (t >= off) ? s[t - off] : 0;
        __syncthreads();
        s[t] += v;
        __syncthreads();
    }
    if (t < NBUCKETS) boff[t] = s[t] - x;
    if (t == 0) boff[NBUCKETS] = N_EDGES;
}

// per-bucket row sort from padded source range; 512 blocks x 1024 threads
// = 2 blocks/CU (32 waves). Pass-1 histogram uses 8 sub-copies (t&7) to cut
// same-address LDS atomic contention ~4.4-way -> ~1.3-way.
__global__ __launch_bounds__(1024) void k_sortA(const int* __restrict__ gcur,
                                                const int* __restrict__ boff,
                                                const int2* __restrict__ pairs1,
                                                int2* __restrict__ pairs2,
                                                int* __restrict__ row_ptr) {
    __shared__ int cnt8[8][RPB];  // pass-1 sub-histograms (stride 293: odd -> copies hit distinct banks)
    __shared__ int cnt[RPB];      // placement cursors
    __shared__ int s[RPB];        // scan scratch
    int b = blockIdx.x;
    int t = threadIdx.x;
    for (int i = t; i < 8 * RPB; i += 1024) ((int*)cnt8)[i] = 0;
    __syncthreads();
    int beg = b * CAP_B;
    int end = gcur[b];
    int cpy = t & 7;
    {
        int e = beg + t;
        for (; e + 7 * 1024 < end; e += 8 * 1024) {
            int r_[8];
#pragma unroll
            for (int j = 0; j < 8; ++j)
                r_[j] = ((unsigned)pairs1[e + j * 1024].x) >> 18;  // cached: reused by pass 2
#pragma unroll
            for (int j = 0; j < 8; ++j) atomicAdd(&cnt8[cpy][r_[j]], 1);
        }
        for (; e < end; e += 1024)
            atomicAdd(&cnt8[cpy][((unsigned)pairs1[e].x) >> 18], 1);
    }
    __syncthreads();
    int x = 0;
    if (t < RPB) {
#pragma unroll
        for (int c2 = 0; c2 < 8; ++c2) x += cnt8[c2][t];
        s[t] = x;
    }
    __syncthreads();
    for (int off = 1; off < RPB; off <<= 1) {
        int v = (t >= off && t < RPB) ? s[t - off] : 0;
        __syncthreads();
        if (t < RPB) s[t] += v;
        __syncthreads();
    }
    if (t < RPB) {
        int ex = boff[b] + s[t] - x;
        row_ptr[b * RPB + t] = ex;
        cnt[t] = ex;
    }
    if (b == NBUCKETS - 1 && t == 0) row_ptr[NROWS_PAD] = N_EDGES;
    __syncthreads();
    const long* p1l = (const long*)pairs1;
    {
        int e = beg + t;
        for (; e + 7 * 1024 < end; e += 8 * 1024) {
            long q[8];
#pragma unroll
            for (int j = 0; j < 8; ++j)
                q[j] = __builtin_nontemporal_load(p1l + e + j * 1024);  // last read: NT
#pragma unroll
            for (int j = 0; j < 8; ++j) {
                int x0 = (int)q[j], y0 = (int)(q[j] >> 32);
                int pos = atomicAdd(&cnt[((unsigned)x0) >> 18], 1);
                pairs2[pos] = make_int2(x0 & 0x3FFFF, y0);
            }
        }
        for (; e < end; e += 1024) {
            long q0 = __builtin_nontemporal_load(p1l + e);
            int x0 = (int)q0, y0 = (int)(q0 >> 32);
            int pos = atomicAdd(&cnt[((unsigned)x0) >> 18], 1);
            pairs2[pos] = make_int2(x0 & 0x3FFFF, y0);
        }
    }
}

// ---------------- phase 3: propagation ----------------

// e0b only; acc is no longer materialized (k_spmm_fin reads embs directly).
__global__ void k_init(const f4v* __restrict__ ue, const f4v* __restrict__ ie,
                       ushort4* __restrict__ e0b) {
    int i = blockIdx.x * blockDim.x + threadIdx.x;
    if (i >= NODE_F4) return;
    f4v v = (i < USER_F4) ? __builtin_nontemporal_load(ue + i)
                          : __builtin_nontemporal_load(ie + i - USER_F4);
    e0b[i] = make_ushort4(f2bf(v.x), f2bf(v.y), f2bf(v.z), f2bf(v.w));
}

// 16 lanes/row; lane owns 4 channels (8B ushort4 gather). Unroll-8 (R13 form,
// frozen: divergence fix / masked tail / NT all measured worse).
__global__ __launch_bounds__(256) void k_spmm(const int* __restrict__ row_ptr,
                                              const long* __restrict__ pairs,
                                              const ushort4* __restrict__ cur,
                                              ushort4* __restrict__ nxt) {
    int tid = blockIdx.x * blockDim.x + threadIdx.x;
    int row = tid >> 4;
    if (row >= N_NODES) return;
    int c = tid & 15;
    int beg = row_ptr[row];
    int end = row_ptr[row + 1];
    float4 r = make_float4(0.f, 0.f, 0.f, 0.f);
    int k = beg;
    for (; k + 7 < end; k += 8) {
        long p[8];
        ushort4 g[8];
#pragma unroll
        for (int j = 0; j < 8; ++j) p[j] = pairs[k + j];
#pragma unroll
        for (int j = 0; j < 8; ++j) g[j] = cur[(long)(int)(p[j] & 0x3FFFF) * 16 + c];
#pragma unroll
        for (int j = 0; j < 8; ++j) {
            float v = __int_as_float((int)(p[j] >> 32));
            r.x += v * bf2f(g[j].x);
            r.y += v * bf2f(g[j].y);
            r.z += v * bf2f(g[j].z);
            r.w += v * bf2f(g[j].w);
        }
    }
    for (; k < end; ++k) {
        long p0 = pairs[k];
        ushort4 g0 = cur[(long)(int)(p0 & 0x3FFFF) * 16 + c];
        float v0 = __int_as_float((int)(p0 >> 32));
        r.x += v0 * bf2f(g0.x);
        r.y += v0 * bf2f(g0.y);
        r.z += v0 * bf2f(g0.z);
        r.w += v0 * bf2f(g0.w);
    }
    nxt[(long)row * 16 + c] = make_ushort4(f2bf(r.x), f2bf(r.y), f2bf(r.z), f2bf(r.w));
}

// Final layer: r = SpMM(e2); acc_out = (e0 + e1 + e2 + r) * 0.25,
// with e0 read straight from the f32 embeddings (bit-identical to old acc).
__global__ __launch_bounds__(256) void k_spmm_fin(const int* __restrict__ row_ptr,
                                                  const long* __restrict__ pairs,
                                                  const ushort4* __restrict__ cur,  // e2b
                                                  const ushort4* __restrict__ e1b,
                                                  const f4v* __restrict__ ue,
                                                  const f4v* __restrict__ ie,
                                                  float4* __restrict__ acc) {
    int tid = blockIdx.x * blockDim.x + threadIdx.x;
    int row = tid >> 4;
    if (row >= N_NODES) return;
    int c = tid & 15;
    int beg = row_ptr[row];
    int end = row_ptr[row + 1];
    float4 r = make_float4(0.f, 0.f, 0.f, 0.f);
    int k = beg;
    for (; k + 7 < end; k += 8) {
        long p[8];
        ushort4 g[8];
#pragma unroll
        for (int j = 0; j < 8; ++j) p[j] = pairs[k + j];
#pragma unroll
        for (int j = 0; j < 8; ++j) g[j] = cur[(long)(int)(p[j] & 0x3FFFF) * 16 + c];
#pragma unroll
        for (int j = 0; j < 8; ++j) {
            float v = __int_as_float((int)(p[j] >> 32));
            r.x += v * bf2f(g[j].x);
            r.y += v * bf2f(g[j].y);
            r.z += v * bf2f(g[j].z);
            r.w += v * bf2f(g[j].w);
        }
    }
    for (; k < end; ++k) {
        long p0 = pairs[k];
        ushort4 g0 = cur[(long)(int)(p0 & 0x3FFFF) * 16 + c];
        float v0 = __int_as_float((int)(p0 >> 32));
        r.x += v0 * bf2f(g0.x);
        r.y += v0 * bf2f(g0.y);
        r.z += v0 * bf2f(g0.z);
        r.w += v0 * bf2f(g0.w);
    }
    long o = (long)row * 16 + c;
    f4v e0 = (row < NUM_USERS) ? ue[o] : ie[o - (long)NUM_USERS * 16];
    ushort4 e1 = e1b[o];
    ushort4 e2 = cur[o];
    float4 a;
    a.x = (e0.x + bf2f(e1.x) + bf2f(e2.x) + r.x) * 0.25f;
    a.y = (e0.y + bf2f(e1.y) + bf2f(e2.y) + r.y) * 0.25f;
    a.z = (e0.z + bf2f(e1.z) + bf2f(e2.z) + r.z) * 0.25f;
    a.w = (e0.w + bf2f(e1.w) + bf2f(e2.w) + r.w) * 0.25f;
    acc[o] = a;
}

// ---------------- R0 fallback (atomic scatter) for small ws ----------------

__global__ void lgcn_init(const float4* __restrict__ user_emb,
                          const float4* __restrict__ item_emb,
                          float4* __restrict__ cur, float4* __restrict__ nxt,
                          float4* __restrict__ acc) {
    int i = blockIdx.x * blockDim.x + threadIdx.x;
    if (i >= NODE_F4) return;
    float4 v = (i < USER_F4) ? user_emb[i] : item_emb[i - USER_F4];
    cur[i] = v; acc[i] = v; nxt[i] = make_float4(0.f, 0.f, 0.f, 0.f);
}

__global__ void lgcn_scatter(const int* __restrict__ src, const int* __restrict__ dst,
                             const float* __restrict__ val,
                             const float4* __restrict__ cur, float* __restrict__ nxt) {
    int tid = blockIdx.x * blockDim.x + threadIdx.x;
    int e = tid >> 4;
    if (e >= N_EDGES) return;
    int c = tid & 15;
    int s = src[e]; int d = dst[e]; float v = val[e];
    float4 m = cur[(long)s * 16 + c];
    float* p = nxt + (long)d * 64 + c * 4;
    unsafeAtomicAdd(p + 0, v * m.x);
    unsafeAtomicAdd(p + 1, v * m.y);
    unsafeAtomicAdd(p + 2, v * m.z);
    unsafeAtomicAdd(p + 3, v * m.w);
}

__global__ void lgcn_add_zero(float4* __restrict__ acc, const float4* __restrict__ nxt,
                              float4* __restrict__ other) {
    int i = blockIdx.x * blockDim.x + threadIdx.x;
    if (i >= NODE_F4) return;
    float4 a = acc[i]; float4 n = nxt[i];
    a.x += n.x; a.y += n.y; a.z += n.z; a.w += n.w;
    acc[i] = a;
    other[i] = make_float4(0.f, 0.f, 0.f, 0.f);
}

__global__ void lgcn_final(float4* __restrict__ acc, const float4* __restrict__ nxt) {
    int i = blockIdx.x * blockDim.x + threadIdx.x;
    if (i >= NODE_F4) return;
    float4 a = acc[i]; float4 n = nxt[i];
    a.x = (a.x + n.x) * 0.25f; a.y = (a.y + n.y) * 0.25f;
    a.z = (a.z + n.z) * 0.25f; a.w = (a.w + n.w) * 0.25f;
    acc[i] = a;
}

// ---------------- launch ----------------

extern "C" void kernel_launch(void* const* d_in, const int* in_sizes, int n_in,
                              void* d_out, int out_size, void* d_ws, size_t ws_size,
                              hipStream_t stream) {
    const int*    adj_src  = (const int*)d_in[2];
    const int*    adj_dst  = (const int*)d_in[3];
    const float*  adj_vals = (const float*)d_in[4];
    float* acc = (float*)d_out;

    const int BLK = 256;
    const int grid_node  = (NODE_F4 + BLK - 1) / BLK;        // 9375
    const int grid_row16 = (N_NODES * 16 + BLK - 1) / BLK;   // 9375

    const size_t SZ_PAIRS = (size_t)N_EDGES * 8;             // 48,000,000
    const size_t SZ_P1PAD = (size_t)NBUCKETS * CAP_B * 8;    // 51,118,080
    const size_t SZ_BF    = (size_t)N_NODES * EMB * 2;       // 19,200,000
    const size_t SZ_RP    = 600320;                          // 150017 ints, padded
    const size_t SZ_B     = 4096;
    const size_t NEEDED1  = SZ_PAIRS + SZ_P1PAD + SZ_BF + SZ_RP + 2 * SZ_B;  // ~118.9 MB

    if (ws_size >= NEEDED1) {
        // ---- tier 1: padded buckets ----
        // [0,48M) pairs2 | [48M, +51.1M) pairs1_pad (e0b/e1b alias) |
        // [99.1M, +19.2M) e2b | row_ptr | gcur | boff
        char* w = (char*)d_ws;
        int2*    pairs2 = (int2*)(w);
        int2*    pairs1 = (int2*)(w + SZ_PAIRS);
        ushort4* e0b    = (ushort4*)(w + SZ_PAIRS);            // aliases pairs1
        ushort4* e1b    = (ushort4*)(w + SZ_PAIRS + SZ_BF);    // aliases pairs1
        ushort4* e2b    = (ushort4*)(w + SZ_PAIRS + SZ_P1PAD);
        int*  row_ptr= (int*)(w + SZ_PAIRS + SZ_P1PAD + SZ_BF);
        int*  gcur   = (int*)(w + SZ_PAIRS + SZ_P1PAD + SZ_BF + SZ_RP);
        int*  boff   = (int*)(w + SZ_PAIRS + SZ_P1PAD + SZ_BF + SZ_RP + SZ_B);

        k_ginit<<<(NBUCKETS + BLK - 1) / BLK, BLK, 0, stream>>>(gcur);
        k_part<<<PART_BLOCKS, PTHREADS, 0, stream>>>(adj_src, adj_dst, adj_vals,
                                                     gcur, pairs1);
        k_fill<<<1, 1024, 0, stream>>>(gcur, boff);
        k_sortA<<<NBUCKETS, 1024, 0, stream>>>(gcur, boff, pairs1, pairs2, row_ptr);

        k_init<<<grid_node, BLK, 0, stream>>>((const f4v*)d_in[5], (const f4v*)d_in[6],
                                              e0b);
        k_spmm<<<grid_row16, BLK, 0, stream>>>(row_ptr, (const long*)pairs2, e0b, e1b);
        k_spmm<<<grid_row16, BLK, 0, stream>>>(row_ptr, (const long*)pairs2, e1b, e2b);
        k_spmm_fin<<<grid_row16, BLK, 0, stream>>>(row_ptr, (const long*)pairs2, e2b,
                                                   e1b, (const f4v*)d_in[5],
                                                   (const f4v*)d_in[6], (float4*)acc);
    } else {
        // ---- fallback: atomic scatter ----
        const float4* user_emb = (const float4*)d_in[5];
        const float4* item_emb = (const float4*)d_in[6];
        float* ws0 = (float*)d_ws;
        float* ws1 = ws0 + (size_t)N_NODES * EMB;
        lgcn_init<<<grid_node, BLK, 0, stream>>>(user_emb, item_emb,
                                                 (float4*)ws0, (float4*)ws1, (float4*)acc);
        lgcn_scatter<<<(N_EDGES*16+BLK-1)/BLK, BLK, 0, stream>>>(adj_src, adj_dst, adj_vals,
                                                    (const float4*)ws0, ws1);
        lgcn_add_zero<<<grid_node, BLK, 0, stream>>>((float4*)acc, (const float4*)ws1, (float4*)ws0);
        lgcn_scatter<<<(N_EDGES*16+BLK-1)/BLK, BLK, 0, stream>>>(adj_src, adj_dst, adj_vals,
                                                    (const float4*)ws1, ws0);
        lgcn_add_zero<<<grid_node, BLK, 0, stream>>>((float4*)acc, (const float4*)ws0, (float4*)ws1);
        lgcn_scatter<<<(N_EDGES*16+BLK-1)/BLK, BLK, 0, stream>>>(adj_src, adj_dst, adj_vals,
                                                    (const float4*)ws0, ws1);
        lgcn_final<<<grid_node, BLK, 0, stream>>>((float4*)acc, (const float4*)ws1);
    }
}